// Round 17
// baseline (152.851 us; speedup 1.0000x reference)
//
#include <hip/hip_runtime.h>
#include <stdint.h>

typedef __attribute__((ext_vector_type(8))) short short8;
typedef __attribute__((ext_vector_type(4))) float f32x4;

#define SB __builtin_amdgcn_sched_barrier(0)

__device__ __forceinline__ unsigned short f2bf(float f) {
  unsigned u = __float_as_uint(f);
  u += 0x7FFF + ((u >> 16) & 1);
  return (unsigned short)(u >> 16);
}

// Packed fragment layout (k-major) for mfma_f32_16x16x32_bf16 operands:
// frag tile (rt, kc): short off = (kc*NRT + rt)*512 + L*8 + e,
// L = (row&15) + 16*((k&31)>>3), e = k&7. 1 frag = wave-contiguous 1KB.
// Per-head planes (28KB = 14336 shorts): Q/K: 14 rt (n) x 2 kc (d);
// Vt: 4 rt (d) x 7 kc (n), tile index kc*4+rt.

// ---------------- merged prep (parallel, barrier-free x-pack) ----------------
// blocks [0,4728): x-pack, one WAVE per (mt,kc) tile (18912 wave-tasks)
// blocks [4728,5880): weight pack + LoRA fold (W' = W + 2*lb@la)
// blocks [5880,6072): zero V seq-pad in packed Vt layout
__global__ __launch_bounds__(256) void k_prep4(const float* __restrict__ x,
                                               const float* __restrict__ qkv_w,
                                               const float* __restrict__ out_w,
                                               const float* __restrict__ qkv_la,
                                               const float* __restrict__ qkv_lb,
                                               const float* __restrict__ out_la,
                                               const float* __restrict__ out_lb,
                                               unsigned short* __restrict__ Apk,
                                               unsigned short* __restrict__ Wq,
                                               unsigned short* __restrict__ Wo,
                                               unsigned short* __restrict__ Vtpk) {
  const int bid = blockIdx.x;
  const int t = threadIdx.x;
  const int w = t >> 6, l = t & 63;
  if (bid < 4728) {
    // x-pack: task = (mt, kc); lane L = (row&15) + 16*(kquad)
    const int task = bid * 4 + w;           // [0, 18912)
    const int mt = task / 24, kc = task - mt * 24;
    const float* src = x + (size_t)(mt * 16 + (l & 15)) * 768 + kc * 32 + (l >> 4) * 8;
    float4 a = *(const float4*)src;
    float4 b = *(const float4*)(src + 4);
    short8 o;
    o[0] = f2bf(a.x); o[1] = f2bf(a.y); o[2] = f2bf(a.z); o[3] = f2bf(a.w);
    o[4] = f2bf(b.x); o[5] = f2bf(b.y); o[6] = f2bf(b.z); o[7] = f2bf(b.w);
    *(short8*)(Apk + (size_t)(kc * 788 + mt) * 512 + l * 8) = o;
  } else if (bid < 5880) {
    const bool isq = bid < 5592;
    const float* W = isq ? qkv_w : out_w;
    const float* la = isq ? qkv_la : out_la;
    const float* lb = isq ? qkv_lb : out_lb;
    unsigned short* dst = isq ? Wq : Wo;
    const int NRT = isq ? 144 : 48;
    const int base = isq ? 4728 : 5592;
    int wv = ((bid - base) * 256 + t) >> 6;
    int rt = wv / 24, kc = wv - rt * 24;
    int lr = l & 15;
    const int o = rt * 16 + lr;
    const int d0 = kc * 32 + (l >> 4) * 8;
    const float* src = W + (size_t)o * 768 + d0;
    float4 a = *(const float4*)src;
    float4 b = *(const float4*)(src + 4);
    float wvv[8] = {a.x, a.y, a.z, a.w, b.x, b.y, b.z, b.w};
    const float4* lb4 = (const float4*)(lb + (size_t)o * 8);
    float4 p0 = lb4[0], p1 = lb4[1];
    float lbv[8] = {p0.x, p0.y, p0.z, p0.w, p1.x, p1.y, p1.z, p1.w};
#pragma unroll
    for (int r = 0; r < 8; ++r) {
      const float4* la4 = (const float4*)(la + (size_t)r * 768 + d0);
      float4 c = la4[0], dd = la4[1];
      float s = 2.0f * lbv[r];
      wvv[0] += s * c.x;  wvv[1] += s * c.y;  wvv[2] += s * c.z;  wvv[3] += s * c.w;
      wvv[4] += s * dd.x; wvv[5] += s * dd.y; wvv[6] += s * dd.z; wvv[7] += s * dd.w;
    }
    short8 oo;
#pragma unroll
    for (int e = 0; e < 8; ++e) oo[e] = f2bf(wvv[e]);
    *(short8*)(dst + (size_t)(kc * NRT + rt) * 512 + l * 8) = oo;
  } else {
    // zero V seq-pad in PACKED Vt layout: thread r = bh*64+hd, n in [197,224)
    int r = (bid - 5880) * 256 + t;  // [0, 49152)
    int bh = r >> 6, hd = r & 63;
    unsigned short* base = Vtpk + (size_t)bh * 14336 + (24 + (hd >> 4)) * 512;  // kc=6 plane
#pragma unroll
    for (int c = 0; c < 27; ++c) {
      int n = 197 + c;
      base[((hd & 15) + 16 * ((n & 31) >> 3)) * 8 + (n & 7)] = 0;
    }
  }
}

// ---------------- GEMM: B via LDS, A reg depth-2, shared-B 4-wave block ----------------
// SLOTS kc-slots in LDS (SLOTS*4KB); refill every SLOTS kt. OCC = min waves/EU.
// MODE 0: qkv (NT=36, NRTB=144) scatter to PACKED Q/K/Vt + bias. MODE 1: out (NT=12, NRTB=48).
template <int MODE, int NT, int NRTB, int SLOTS, int OCC>
__global__ __launch_bounds__(256, OCC) void k_gp4(
    const unsigned short* __restrict__ Apk, const unsigned short* __restrict__ Bpk,
    const float* __restrict__ bias, unsigned short* __restrict__ Qpk,
    unsigned short* __restrict__ Kpk, unsigned short* __restrict__ Vtpk,
    float* __restrict__ outp) {
  __shared__ __align__(16) char bl[SLOTS * 4096];  // SLOTS kc-slots x 4 rt x 1KB
  const int w = threadIdx.x >> 6, l = threadIdx.x & 63;
  const int lr = l & 15, lg = l >> 4;
  const int nwg = gridDim.x;
  const int orig = blockIdx.x;
  const int qq = nwg >> 3, rr = nwg & 7, xcd = orig & 7;
  const int wgid = (xcd < rr ? xcd * (qq + 1) : rr * (qq + 1) + (xcd - rr) * qq) + (orig >> 3);
  const int mg = wgid / NT, nt = wgid - mg * NT;
  int mtw = mg * 4 + w;
  if (mtw > 196) mtw = 196;
  const int m0 = mtw * 64, n0 = nt * 64;

  const size_t KSA = 788 * 512;
  const unsigned short* pa = Apk + (size_t)(mtw * 4) * 512 + l * 8;

  auto* lds3 = (__attribute__((address_space(3))) char*)bl;
  auto STB = [&](int kc) {
    const unsigned short* g = Bpk + ((size_t)kc * NRTB + nt * 4 + w) * 512 + l * 8;
    __builtin_amdgcn_global_load_lds((const __attribute__((address_space(1))) void*)g,
                                     (__attribute__((address_space(3))) void*)(lds3 + ((kc % SLOTS) * 4 + w) * 1024),
                                     16, 0, 0);
  };

  f32x4 acc[4][4];
#pragma unroll
  for (int i = 0; i < 4; ++i)
#pragma unroll
    for (int j = 0; j < 4; ++j) acc[i][j] = (f32x4){0.f, 0.f, 0.f, 0.f};

  short8 ab[2][4];
#define LDA4(dst, kt) \
  { const unsigned short* q_ = pa + (size_t)(kt) * KSA; \
    dst[0] = *(const short8*)(q_); dst[1] = *(const short8*)(q_ + 512); \
    dst[2] = *(const short8*)(q_ + 1024); dst[3] = *(const short8*)(q_ + 1536); }

#pragma unroll
  for (int kc = 0; kc < SLOTS; ++kc) STB(kc);
  asm volatile("s_waitcnt vmcnt(0)" ::: "memory");
  SB;
  __builtin_amdgcn_s_barrier();
  LDA4(ab[0], 0);
  LDA4(ab[1], 1);

#pragma unroll
  for (int kt = 0; kt < 24; ++kt) {
    if (kt != 0 && (kt % SLOTS) == 0) {
      asm volatile("s_waitcnt vmcnt(4)" ::: "memory");
      SB;
      __builtin_amdgcn_s_barrier();
    }
    short8 bfr[4];
    const char* sbase = (const char*)bl + (kt % SLOTS) * 4096;
#pragma unroll
    for (int nf = 0; nf < 4; ++nf)
      bfr[nf] = *(const short8*)(sbase + nf * 1024 + l * 16);
    if ((kt % SLOTS) == SLOTS - 1 && kt < 23) {
      asm volatile("s_waitcnt lgkmcnt(0)" ::: "memory");
      SB;
      __builtin_amdgcn_s_barrier();
#pragma unroll
      for (int kc2 = 1; kc2 <= SLOTS; ++kc2)
        if (kt + kc2 < 24) STB(kt + kc2);
    }
    __builtin_amdgcn_s_setprio(1);
#pragma unroll
    for (int mf = 0; mf < 4; ++mf)
#pragma unroll
      for (int nf = 0; nf < 4; ++nf)
        acc[mf][nf] = __builtin_amdgcn_mfma_f32_16x16x32_bf16(ab[kt & 1][mf], bfr[nf], acc[mf][nf], 0, 0, 0);
    __builtin_amdgcn_s_setprio(0);
    if (kt + 2 < 24) LDA4(ab[kt & 1], kt + 2);
  }
#undef LDA4

  // epilogue: bias; MODE 0 scatter into PACKED per-head fragment planes
  float bo[4];
#pragma unroll
  for (int nf = 0; nf < 4; ++nf) bo[nf] = bias[n0 + nf * 16 + lr];
  const int which = nt / 12;
  const int hh = nt - which * 12;
#pragma unroll
  for (int mf = 0; mf < 4; ++mf) {
#pragma unroll
    for (int v = 0; v < 4; ++v) {
      int m = m0 + mf * 16 + lg * 4 + v;
      int b = m / 197;
      int n = m - b * 197;
#pragma unroll
      for (int nf = 0; nf < 4; ++nf) {
        float val = acc[mf][nf][v] + bo[nf];
        if (MODE == 0) {
          int bh = b * 12 + hh;
          unsigned short hv = f2bf(val);
          if (which == 2) {
            Vtpk[(size_t)bh * 14336 + ((n >> 5) * 4 + nf) * 512 +
                 (lr + 16 * ((n & 31) >> 3)) * 8 + (n & 7)] = hv;
          } else {
            unsigned short* dst = (which == 0) ? Qpk : Kpk;
            dst[(size_t)bh * 14336 + ((nf >> 1) * 14 + (n >> 4)) * 512 +
                ((n & 15) + 16 * ((nf & 1) * 2 + (lr >> 3))) * 8 + (lr & 7)] = hv;
          }
        } else {
          outp[(size_t)m * 768 + n0 + nf * 16 + lr] = val;
        }
      }
    }
  }
}

// ---------------- attention: one WAVE per (bh, q-tile); 4 waves/block ----------------
__global__ __launch_bounds__(256) void k_attn_w(const unsigned short* __restrict__ Qpk,
                                                const unsigned short* __restrict__ Kpk,
                                                const unsigned short* __restrict__ Vtpk,
                                                unsigned short* __restrict__ Apk) {
  __shared__ __align__(16) unsigned short Ps[4][7 * 512];
  const int w = threadIdx.x >> 6, l = threadIdx.x & 63;
  const int lr = l & 15, lg = l >> 4;
  const int nwg = gridDim.x;
  const int orig = blockIdx.x;
  const int qq = nwg >> 3, xcd = orig & 7;
  const int wgid = xcd * qq + (orig >> 3);
  const int task = wgid * 4 + w;  // [0, 9984)
  const int bh = task / 13, t = task - bh * 13;
  const int b = bh / 12, h = bh - b * 12;
  const unsigned short* Qb = Qpk + (size_t)bh * 14336;
  const unsigned short* Kb = Kpk + (size_t)bh * 14336;
  const unsigned short* Vb = Vtpk + (size_t)bh * 14336;

  short8 aq0 = *(const short8*)(Qb + (size_t)t * 512 + l * 8);
  short8 aq1 = *(const short8*)(Qb + (size_t)(14 + t) * 512 + l * 8);
  f32x4 s[13];
#pragma unroll
  for (int jt = 0; jt < 13; ++jt) {  // jt=13 is all-pad: skipped, P=0
    f32x4 a = (f32x4){0.f, 0.f, 0.f, 0.f};
    short8 bk0 = *(const short8*)(Kb + (size_t)jt * 512 + l * 8);
    short8 bk1 = *(const short8*)(Kb + (size_t)(14 + jt) * 512 + l * 8);
    __builtin_amdgcn_s_setprio(1);
    a = __builtin_amdgcn_mfma_f32_16x16x32_bf16(aq0, bk0, a, 0, 0, 0);
    a = __builtin_amdgcn_mfma_f32_16x16x32_bf16(aq1, bk1, a, 0, 0, 0);
    __builtin_amdgcn_s_setprio(0);
    s[jt] = a;
  }
#pragma unroll
  for (int v = 0; v < 4; ++v)
    if (lr >= 5) s[12][v] = -1.0e30f;
  float mx[4] = {-3.0e38f, -3.0e38f, -3.0e38f, -3.0e38f};
#pragma unroll
  for (int jt = 0; jt < 13; ++jt)
#pragma unroll
    for (int v = 0; v < 4; ++v) mx[v] = fmaxf(mx[v], s[jt][v]);
#pragma unroll
  for (int v = 0; v < 4; ++v) {
    mx[v] = fmaxf(mx[v], __shfl_xor(mx[v], 1));
    mx[v] = fmaxf(mx[v], __shfl_xor(mx[v], 2));
    mx[v] = fmaxf(mx[v], __shfl_xor(mx[v], 4));
    mx[v] = fmaxf(mx[v], __shfl_xor(mx[v], 8));
  }
  float sum[4] = {0.f, 0.f, 0.f, 0.f};
  const float cc = 0.125f * 1.44269504088896341f;
#pragma unroll
  for (int jt = 0; jt < 13; ++jt)
#pragma unroll
    for (int v = 0; v < 4; ++v) {
      float pv = exp2f((s[jt][v] - mx[v]) * cc);
      s[jt][v] = pv;
      sum[v] += pv;
    }
#pragma unroll
  for (int v = 0; v < 4; ++v) {
    sum[v] += __shfl_xor(sum[v], 1);
    sum[v] += __shfl_xor(sum[v], 2);
    sum[v] += __shfl_xor(sum[v], 4);
    sum[v] += __shfl_xor(sum[v], 8);
  }
  float inv[4];
#pragma unroll
  for (int v = 0; v < 4; ++v) inv[v] = 1.0f / sum[v];
  unsigned short* pw = &Ps[w][0];
#pragma unroll
  for (int jt = 0; jt < 13; ++jt) {
    const int base = (jt >> 1) * 512 + ((jt & 1) * 2 + (lr >> 3)) * 128 + (lr & 7);
#pragma unroll
    for (int v = 0; v < 4; ++v)
      pw[base + (lg * 4 + v) * 8] = f2bf(s[jt][v] * inv[v]);
  }
  {  // jt=13 pad tile: P = 0
    const int base = 6 * 512 + (2 + (lr >> 3)) * 128 + (lr & 7);
#pragma unroll
    for (int v = 0; v < 4; ++v) pw[base + (lg * 4 + v) * 8] = 0;
  }
  f32x4 oacc[4];
#pragma unroll
  for (int jo = 0; jo < 4; ++jo) oacc[jo] = (f32x4){0.f, 0.f, 0.f, 0.f};
#pragma unroll
  for (int kk = 0; kk < 7; ++kk) {
    short8 pa = *(const short8*)(pw + kk * 512 + l * 8);
    __builtin_amdgcn_s_setprio(1);
#pragma unroll
    for (int jo = 0; jo < 4; ++jo) {
      short8 bv = *(const short8*)(Vb + (size_t)(kk * 4 + jo) * 512 + l * 8);
      oacc[jo] = __builtin_amdgcn_mfma_f32_16x16x32_bf16(pa, bv, oacc[jo], 0, 0, 0);
    }
    __builtin_amdgcn_s_setprio(0);
  }
  const int q0 = t * 16;
#pragma unroll
  for (int jo = 0; jo < 4; ++jo) {
    const int kc = h * 2 + (jo >> 1);
    const int lgp = (jo & 1) * 2 + (lr >> 3);
    const int e = lr & 7;
#pragma unroll
    for (int v = 0; v < 4; ++v) {
      int n = q0 + lg * 4 + v;
      if (n < 197) {
        int m = b * 197 + n;
        Apk[((size_t)(kc * 788 + (m >> 4)) * 64 + (m & 15) + 16 * lgp) * 8 + e] = f2bf(oacc[jo][v]);
      }
    }
  }
}

extern "C" void kernel_launch(void* const* d_in, const int* in_sizes, int n_in,
                              void* d_out, int out_size, void* d_ws, size_t ws_size,
                              hipStream_t stream) {
  const float* x      = (const float*)d_in[0];
  const float* qkv_w  = (const float*)d_in[1];
  const float* qkv_b  = (const float*)d_in[2];
  const float* qkv_la = (const float*)d_in[3];
  const float* qkv_lb = (const float*)d_in[4];
  const float* out_w  = (const float*)d_in[5];
  const float* out_b  = (const float*)d_in[6];
  const float* out_la = (const float*)d_in[7];
  const float* out_lb = (const float*)d_in[8];
  float* out = (float*)d_out;

  char* p = (char*)d_ws;
  auto carve = [&](size_t bytes) {
    char* r = p;
    p += (bytes + 255) & ~(size_t)255;
    return r;
  };
  unsigned short* Apk  = (unsigned short*)carve((size_t)788 * 24 * 512 * 2 + 32768);
  unsigned short* Wqpk = (unsigned short*)carve((size_t)144 * 24 * 512 * 2);
  unsigned short* Wopk = (unsigned short*)carve((size_t)48 * 24 * 512 * 2);
  unsigned short* Qpk  = (unsigned short*)carve((size_t)768 * 14336 * 2);
  unsigned short* Kpk  = (unsigned short*)carve((size_t)768 * 14336 * 2);
  unsigned short* Vtpk = (unsigned short*)carve((size_t)768 * 14336 * 2);

  // prep: 4728 (x-pack, wave-per-tile) + 864 (qkv_w fold) + 288 (out_w fold) + 192 (V pads)
  k_prep4<<<6072, 256, 0, stream>>>(x, qkv_w, out_w, qkv_la, qkv_lb, out_la, out_lb,
                                    Apk, Wqpk, Wopk, Vtpk);
  // qkv: 50 mg x 36 nt (block = 256x64); 8-slot LDS (32KB), 4 blocks/CU
  k_gp4<0, 36, 144, 8, 4><<<50 * 36, 256, 0, stream>>>(Apk, Wqpk, qkv_b, Qpk, Kpk, Vtpk, nullptr);
  // attention: 9984 wave-tasks = 2496 blocks x 4 waves
  k_attn_w<<<2496, 256, 0, stream>>>(Qpk, Kpk, Vtpk, Apk);  // Apk now holds packed attn-out
  // out: 50 mg x 12 nt; 8-slot LDS, 4 blocks/CU
  k_gp4<1, 12, 48, 8, 4><<<50 * 12, 256, 0, stream>>>(Apk, Wopk, out_b, nullptr, nullptr, nullptr, out);
}

// Round 18
// 150.045 us; speedup vs baseline: 1.0187x; 1.0187x over previous
//
#include <hip/hip_runtime.h>
#include <stdint.h>

typedef __attribute__((ext_vector_type(8))) short short8;
typedef __attribute__((ext_vector_type(4))) float f32x4;

#define SB __builtin_amdgcn_sched_barrier(0)

__device__ __forceinline__ unsigned short f2bf(float f) {
  unsigned u = __float_as_uint(f);
  u += 0x7FFF + ((u >> 16) & 1);
  return (unsigned short)(u >> 16);
}

// Packed fragment layout (k-major) for mfma_f32_16x16x32_bf16 operands:
// frag tile (rt, kc): short off = (kc*NRT + rt)*512 + L*8 + e,
// L = (row&15) + 16*((k&31)>>3), e = k&7. 1 frag = wave-contiguous 1KB.
// Per-head planes (28KB = 14336 shorts): Q/K: 14 rt (n) x 2 kc (d);
// Vt: 4 rt (d) x 7 kc (n), tile index kc*4+rt.

// ---------------- merged prep (parallel, barrier-free x-pack) ----------------
__global__ __launch_bounds__(256) void k_prep4(const float* __restrict__ x,
                                               const float* __restrict__ qkv_w,
                                               const float* __restrict__ out_w,
                                               const float* __restrict__ qkv_la,
                                               const float* __restrict__ qkv_lb,
                                               const float* __restrict__ out_la,
                                               const float* __restrict__ out_lb,
                                               unsigned short* __restrict__ Apk,
                                               unsigned short* __restrict__ Wq,
                                               unsigned short* __restrict__ Wo,
                                               unsigned short* __restrict__ Vtpk) {
  const int bid = blockIdx.x;
  const int t = threadIdx.x;
  const int w = t >> 6, l = t & 63;
  if (bid < 4728) {
    const int task = bid * 4 + w;           // [0, 18912)
    const int mt = task / 24, kc = task - mt * 24;
    const float* src = x + (size_t)(mt * 16 + (l & 15)) * 768 + kc * 32 + (l >> 4) * 8;
    float4 a = *(const float4*)src;
    float4 b = *(const float4*)(src + 4);
    short8 o;
    o[0] = f2bf(a.x); o[1] = f2bf(a.y); o[2] = f2bf(a.z); o[3] = f2bf(a.w);
    o[4] = f2bf(b.x); o[5] = f2bf(b.y); o[6] = f2bf(b.z); o[7] = f2bf(b.w);
    *(short8*)(Apk + (size_t)(kc * 788 + mt) * 512 + l * 8) = o;
  } else if (bid < 5880) {
    const bool isq = bid < 5592;
    const float* W = isq ? qkv_w : out_w;
    const float* la = isq ? qkv_la : out_la;
    const float* lb = isq ? qkv_lb : out_lb;
    unsigned short* dst = isq ? Wq : Wo;
    const int NRT = isq ? 144 : 48;
    const int base = isq ? 4728 : 5592;
    int wv = ((bid - base) * 256 + t) >> 6;
    int rt = wv / 24, kc = wv - rt * 24;
    int lr = l & 15;
    const int o = rt * 16 + lr;
    const int d0 = kc * 32 + (l >> 4) * 8;
    const float* src = W + (size_t)o * 768 + d0;
    float4 a = *(const float4*)src;
    float4 b = *(const float4*)(src + 4);
    float wvv[8] = {a.x, a.y, a.z, a.w, b.x, b.y, b.z, b.w};
    const float4* lb4 = (const float4*)(lb + (size_t)o * 8);
    float4 p0 = lb4[0], p1 = lb4[1];
    float lbv[8] = {p0.x, p0.y, p0.z, p0.w, p1.x, p1.y, p1.z, p1.w};
#pragma unroll
    for (int r = 0; r < 8; ++r) {
      const float4* la4 = (const float4*)(la + (size_t)r * 768 + d0);
      float4 c = la4[0], dd = la4[1];
      float s = 2.0f * lbv[r];
      wvv[0] += s * c.x;  wvv[1] += s * c.y;  wvv[2] += s * c.z;  wvv[3] += s * c.w;
      wvv[4] += s * dd.x; wvv[5] += s * dd.y; wvv[6] += s * dd.z; wvv[7] += s * dd.w;
    }
    short8 oo;
#pragma unroll
    for (int e = 0; e < 8; ++e) oo[e] = f2bf(wvv[e]);
    *(short8*)(dst + (size_t)(kc * NRT + rt) * 512 + l * 8) = oo;
  } else {
    int r = (bid - 5880) * 256 + t;  // [0, 49152)
    int bh = r >> 6, hd = r & 63;
    unsigned short* base = Vtpk + (size_t)bh * 14336 + (24 + (hd >> 4)) * 512;  // kc=6 plane
#pragma unroll
    for (int c = 0; c < 27; ++c) {
      int n = 197 + c;
      base[((hd & 15) + 16 * ((n & 31) >> 3)) * 8 + (n & 7)] = 0;
    }
  }
}

// ---------------- GEMM: B via LDS, A reg depth-2, shared-B 4-wave block ----------------
template <int MODE, int NT, int NRTB, int SLOTS, int OCC>
__global__ __launch_bounds__(256, OCC) void k_gp4(
    const unsigned short* __restrict__ Apk, const unsigned short* __restrict__ Bpk,
    const float* __restrict__ bias, unsigned short* __restrict__ Qpk,
    unsigned short* __restrict__ Kpk, unsigned short* __restrict__ Vtpk,
    float* __restrict__ outp) {
  __shared__ __align__(16) char bl[SLOTS * 4096];
  const int w = threadIdx.x >> 6, l = threadIdx.x & 63;
  const int lr = l & 15, lg = l >> 4;
  const int nwg = gridDim.x;
  const int orig = blockIdx.x;
  const int qq = nwg >> 3, rr = nwg & 7, xcd = orig & 7;
  const int wgid = (xcd < rr ? xcd * (qq + 1) : rr * (qq + 1) + (xcd - rr) * qq) + (orig >> 3);
  const int mg = wgid / NT, nt = wgid - mg * NT;
  int mtw = mg * 4 + w;
  if (mtw > 196) mtw = 196;
  const int m0 = mtw * 64, n0 = nt * 64;

  const size_t KSA = 788 * 512;
  const unsigned short* pa = Apk + (size_t)(mtw * 4) * 512 + l * 8;

  auto* lds3 = (__attribute__((address_space(3))) char*)bl;
  auto STB = [&](int kc) {
    const unsigned short* g = Bpk + ((size_t)kc * NRTB + nt * 4 + w) * 512 + l * 8;
    __builtin_amdgcn_global_load_lds((const __attribute__((address_space(1))) void*)g,
                                     (__attribute__((address_space(3))) void*)(lds3 + ((kc % SLOTS) * 4 + w) * 1024),
                                     16, 0, 0);
  };

  f32x4 acc[4][4];
#pragma unroll
  for (int i = 0; i < 4; ++i)
#pragma unroll
    for (int j = 0; j < 4; ++j) acc[i][j] = (f32x4){0.f, 0.f, 0.f, 0.f};

  short8 ab[2][4];
#define LDA4(dst, kt) \
  { const unsigned short* q_ = pa + (size_t)(kt) * KSA; \
    dst[0] = *(const short8*)(q_); dst[1] = *(const short8*)(q_ + 512); \
    dst[2] = *(const short8*)(q_ + 1024); dst[3] = *(const short8*)(q_ + 1536); }

#pragma unroll
  for (int kc = 0; kc < SLOTS; ++kc) STB(kc);
  asm volatile("s_waitcnt vmcnt(0)" ::: "memory");
  SB;
  __builtin_amdgcn_s_barrier();
  LDA4(ab[0], 0);
  LDA4(ab[1], 1);

#pragma unroll
  for (int kt = 0; kt < 24; ++kt) {
    if (kt != 0 && (kt % SLOTS) == 0) {
      asm volatile("s_waitcnt vmcnt(4)" ::: "memory");
      SB;
      __builtin_amdgcn_s_barrier();
    }
    short8 bfr[4];
    const char* sbase = (const char*)bl + (kt % SLOTS) * 4096;
#pragma unroll
    for (int nf = 0; nf < 4; ++nf)
      bfr[nf] = *(const short8*)(sbase + nf * 1024 + l * 16);
    if ((kt % SLOTS) == SLOTS - 1 && kt < 23) {
      asm volatile("s_waitcnt lgkmcnt(0)" ::: "memory");
      SB;
      __builtin_amdgcn_s_barrier();
#pragma unroll
      for (int kc2 = 1; kc2 <= SLOTS; ++kc2)
        if (kt + kc2 < 24) STB(kt + kc2);
    }
    __builtin_amdgcn_s_setprio(1);
#pragma unroll
    for (int mf = 0; mf < 4; ++mf)
#pragma unroll
      for (int nf = 0; nf < 4; ++nf)
        acc[mf][nf] = __builtin_amdgcn_mfma_f32_16x16x32_bf16(ab[kt & 1][mf], bfr[nf], acc[mf][nf], 0, 0, 0);
    __builtin_amdgcn_s_setprio(0);
    if (kt + 2 < 24) LDA4(ab[kt & 1], kt + 2);
  }
#undef LDA4

  float bo[4];
#pragma unroll
  for (int nf = 0; nf < 4; ++nf) bo[nf] = bias[n0 + nf * 16 + lr];
  const int which = nt / 12;
  const int hh = nt - which * 12;
#pragma unroll
  for (int mf = 0; mf < 4; ++mf) {
#pragma unroll
    for (int v = 0; v < 4; ++v) {
      int m = m0 + mf * 16 + lg * 4 + v;
      int b = m / 197;
      int n = m - b * 197;
#pragma unroll
      for (int nf = 0; nf < 4; ++nf) {
        float val = acc[mf][nf][v] + bo[nf];
        if (MODE == 0) {
          int bh = b * 12 + hh;
          unsigned short hv = f2bf(val);
          if (which == 2) {
            Vtpk[(size_t)bh * 14336 + ((n >> 5) * 4 + nf) * 512 +
                 (lr + 16 * ((n & 31) >> 3)) * 8 + (n & 7)] = hv;
          } else {
            unsigned short* dst = (which == 0) ? Qpk : Kpk;
            dst[(size_t)bh * 14336 + ((nf >> 1) * 14 + (n >> 4)) * 512 +
                ((n & 15) + 16 * ((nf & 1) * 2 + (lr >> 3))) * 8 + (lr & 7)] = hv;
          }
        } else {
          outp[(size_t)m * 768 + n0 + nf * 16 + lr] = val;
        }
      }
    }
  }
}

// ---------------- attention: block per (b,h); K+V staged in LDS once; 8 waves ----------------
__global__ __launch_bounds__(512) void k_attn_b(const unsigned short* __restrict__ Qpk,
                                                const unsigned short* __restrict__ Kpk,
                                                const unsigned short* __restrict__ Vtpk,
                                                unsigned short* __restrict__ Apk) {
  __shared__ __align__(16) unsigned short Ks[14336];
  __shared__ __align__(16) unsigned short Vs[14336];
  __shared__ __align__(16) unsigned short Ps[8][7 * 512];
  const int w = threadIdx.x >> 6, l = threadIdx.x & 63;
  const int lr = l & 15, lg = l >> 4;
  // bijective XCD swizzle (nwg = 768, divisible by 8)
  const int nwg = gridDim.x;
  const int orig = blockIdx.x;
  const int qq = nwg >> 3, xcd = orig & 7;
  const int bh = xcd * qq + (orig >> 3);
  const int b = bh / 12, h = bh - b * 12;
  const unsigned short* Qb = Qpk + (size_t)bh * 14336;
  const unsigned short* Kb = Kpk + (size_t)bh * 14336;
  const unsigned short* Vb = Vtpk + (size_t)bh * 14336;

  // stage K and V planes into LDS (28 chunks of 1KB each; wave-contiguous)
  auto* ldsK = (__attribute__((address_space(3))) char*)Ks;
  auto* ldsV = (__attribute__((address_space(3))) char*)Vs;
  for (int c = w; c < 28; c += 8) {
    __builtin_amdgcn_global_load_lds((const __attribute__((address_space(1))) void*)(Kb + c * 512 + l * 8),
                                     (__attribute__((address_space(3))) void*)(ldsK + c * 1024), 16, 0, 0);
    __builtin_amdgcn_global_load_lds((const __attribute__((address_space(1))) void*)(Vb + c * 512 + l * 8),
                                     (__attribute__((address_space(3))) void*)(ldsV + c * 1024), 16, 0, 0);
  }
  asm volatile("s_waitcnt vmcnt(0)" ::: "memory");
  SB;
  __builtin_amdgcn_s_barrier();

  for (int t = w; t < 13; t += 8) {
    short8 aq0 = *(const short8*)(Qb + (size_t)t * 512 + l * 8);
    short8 aq1 = *(const short8*)(Qb + (size_t)(14 + t) * 512 + l * 8);
    f32x4 s[13];
#pragma unroll
    for (int jt = 0; jt < 13; ++jt) {  // jt=13 is all-pad: skipped, P=0
      f32x4 a = (f32x4){0.f, 0.f, 0.f, 0.f};
      short8 bk0 = *(const short8*)(Ks + (size_t)jt * 512 + l * 8);
      short8 bk1 = *(const short8*)(Ks + (size_t)(14 + jt) * 512 + l * 8);
      __builtin_amdgcn_s_setprio(1);
      a = __builtin_amdgcn_mfma_f32_16x16x32_bf16(aq0, bk0, a, 0, 0, 0);
      a = __builtin_amdgcn_mfma_f32_16x16x32_bf16(aq1, bk1, a, 0, 0, 0);
      __builtin_amdgcn_s_setprio(0);
      s[jt] = a;
    }
#pragma unroll
    for (int v = 0; v < 4; ++v)
      if (lr >= 5) s[12][v] = -1.0e30f;
    float mx[4] = {-3.0e38f, -3.0e38f, -3.0e38f, -3.0e38f};
#pragma unroll
    for (int jt = 0; jt < 13; ++jt)
#pragma unroll
      for (int v = 0; v < 4; ++v) mx[v] = fmaxf(mx[v], s[jt][v]);
#pragma unroll
    for (int v = 0; v < 4; ++v) {
      mx[v] = fmaxf(mx[v], __shfl_xor(mx[v], 1));
      mx[v] = fmaxf(mx[v], __shfl_xor(mx[v], 2));
      mx[v] = fmaxf(mx[v], __shfl_xor(mx[v], 4));
      mx[v] = fmaxf(mx[v], __shfl_xor(mx[v], 8));
    }
    float sum[4] = {0.f, 0.f, 0.f, 0.f};
    const float cc = 0.125f * 1.44269504088896341f;
#pragma unroll
    for (int jt = 0; jt < 13; ++jt)
#pragma unroll
      for (int v = 0; v < 4; ++v) {
        float pv = exp2f((s[jt][v] - mx[v]) * cc);
        s[jt][v] = pv;
        sum[v] += pv;
      }
#pragma unroll
    for (int v = 0; v < 4; ++v) {
      sum[v] += __shfl_xor(sum[v], 1);
      sum[v] += __shfl_xor(sum[v], 2);
      sum[v] += __shfl_xor(sum[v], 4);
      sum[v] += __shfl_xor(sum[v], 8);
    }
    float inv[4];
#pragma unroll
    for (int v = 0; v < 4; ++v) inv[v] = 1.0f / sum[v];
    unsigned short* pw = &Ps[w][0];
#pragma unroll
    for (int jt = 0; jt < 13; ++jt) {
      const int base = (jt >> 1) * 512 + ((jt & 1) * 2 + (lr >> 3)) * 128 + (lr & 7);
#pragma unroll
      for (int v = 0; v < 4; ++v)
        pw[base + (lg * 4 + v) * 8] = f2bf(s[jt][v] * inv[v]);
    }
    {  // jt=13 pad tile: P = 0
      const int base = 6 * 512 + (2 + (lr >> 3)) * 128 + (lr & 7);
#pragma unroll
      for (int v = 0; v < 4; ++v) pw[base + (lg * 4 + v) * 8] = 0;
    }
    f32x4 oacc[4];
#pragma unroll
    for (int jo = 0; jo < 4; ++jo) oacc[jo] = (f32x4){0.f, 0.f, 0.f, 0.f};
#pragma unroll
    for (int kk = 0; kk < 7; ++kk) {
      short8 pa = *(const short8*)(pw + kk * 512 + l * 8);
      __builtin_amdgcn_s_setprio(1);
#pragma unroll
      for (int jo = 0; jo < 4; ++jo) {
        short8 bv = *(const short8*)(Vs + (size_t)(kk * 4 + jo) * 512 + l * 8);
        oacc[jo] = __builtin_amdgcn_mfma_f32_16x16x32_bf16(pa, bv, oacc[jo], 0, 0, 0);
      }
      __builtin_amdgcn_s_setprio(0);
    }
    const int q0 = t * 16;
#pragma unroll
    for (int jo = 0; jo < 4; ++jo) {
      const int kc = h * 2 + (jo >> 1);
      const int lgp = (jo & 1) * 2 + (lr >> 3);
      const int e = lr & 7;
#pragma unroll
      for (int v = 0; v < 4; ++v) {
        int n = q0 + lg * 4 + v;
        if (n < 197) {
          int m = b * 197 + n;
          Apk[((size_t)(kc * 788 + (m >> 4)) * 64 + (m & 15) + 16 * lgp) * 8 + e] = f2bf(oacc[jo][v]);
        }
      }
    }
  }
}

extern "C" void kernel_launch(void* const* d_in, const int* in_sizes, int n_in,
                              void* d_out, int out_size, void* d_ws, size_t ws_size,
                              hipStream_t stream) {
  const float* x      = (const float*)d_in[0];
  const float* qkv_w  = (const float*)d_in[1];
  const float* qkv_b  = (const float*)d_in[2];
  const float* qkv_la = (const float*)d_in[3];
  const float* qkv_lb = (const float*)d_in[4];
  const float* out_w  = (const float*)d_in[5];
  const float* out_b  = (const float*)d_in[6];
  const float* out_la = (const float*)d_in[7];
  const float* out_lb = (const float*)d_in[8];
  float* out = (float*)d_out;

  char* p = (char*)d_ws;
  auto carve = [&](size_t bytes) {
    char* r = p;
    p += (bytes + 255) & ~(size_t)255;
    return r;
  };
  unsigned short* Apk  = (unsigned short*)carve((size_t)788 * 24 * 512 * 2 + 32768);
  unsigned short* Wqpk = (unsigned short*)carve((size_t)144 * 24 * 512 * 2);
  unsigned short* Wopk = (unsigned short*)carve((size_t)48 * 24 * 512 * 2);
  unsigned short* Qpk  = (unsigned short*)carve((size_t)768 * 14336 * 2);
  unsigned short* Kpk  = (unsigned short*)carve((size_t)768 * 14336 * 2);
  unsigned short* Vtpk = (unsigned short*)carve((size_t)768 * 14336 * 2);

  // prep: 4728 (x-pack) + 864 (qkv_w fold) + 288 (out_w fold) + 192 (V pads)
  k_prep4<<<6072, 256, 0, stream>>>(x, qkv_w, out_w, qkv_la, qkv_lb, out_la, out_lb,
                                    Apk, Wqpk, Wopk, Vtpk);
  // qkv: 50 mg x 36 nt; 8-slot LDS, 4 blocks/CU
  k_gp4<0, 36, 144, 8, 4><<<50 * 36, 256, 0, stream>>>(Apk, Wqpk, qkv_b, Qpk, Kpk, Vtpk, nullptr);
  // attention: block per (b,h), K+V in LDS
  k_attn_b<<<768, 512, 0, stream>>>(Qpk, Kpk, Vtpk, Apk);  // Apk now holds packed attn-out
  // out: 50 mg x 12 nt; 8-slot LDS, 4 blocks/CU
  k_gp4<1, 12, 48, 8, 4><<<50 * 12, 256, 0, stream>>>(Apk, Wopk, out_b, nullptr, nullptr, nullptr, out);
}

// Round 19
// 140.916 us; speedup vs baseline: 1.0847x; 1.0648x over previous
//
#include <hip/hip_runtime.h>
#include <stdint.h>

typedef __attribute__((ext_vector_type(8))) short short8;
typedef __attribute__((ext_vector_type(4))) float f32x4;

#define SB __builtin_amdgcn_sched_barrier(0)

__device__ __forceinline__ unsigned short f2bf(float f) {
  unsigned u = __float_as_uint(f);
  u += 0x7FFF + ((u >> 16) & 1);
  return (unsigned short)(u >> 16);
}

// Packed fragment layout (k-major) for mfma_f32_16x16x32_bf16 operands:
// frag tile (rt, kc): short off = (kc*NRT + rt)*512 + L*8 + e,
// L = (row&15) + 16*((k&31)>>3), e = k&7. 1 frag = wave-contiguous 1KB.
// Per-head planes (28KB = 14336 shorts): Q/K: 14 rt (n) x 2 kc (d);
// Vt: 4 rt (d) x 7 kc (n), tile index kc*4+rt.

// ---------------- merged prep (parallel, barrier-free x-pack) ----------------
__global__ __launch_bounds__(256) void k_prep4(const float* __restrict__ x,
                                               const float* __restrict__ qkv_w,
                                               const float* __restrict__ out_w,
                                               const float* __restrict__ qkv_la,
                                               const float* __restrict__ qkv_lb,
                                               const float* __restrict__ out_la,
                                               const float* __restrict__ out_lb,
                                               unsigned short* __restrict__ Apk,
                                               unsigned short* __restrict__ Wq,
                                               unsigned short* __restrict__ Wo,
                                               unsigned short* __restrict__ Vtpk) {
  const int bid = blockIdx.x;
  const int t = threadIdx.x;
  const int w = t >> 6, l = t & 63;
  if (bid < 4728) {
    const int task = bid * 4 + w;           // [0, 18912)
    const int mt = task / 24, kc = task - mt * 24;
    const float* src = x + (size_t)(mt * 16 + (l & 15)) * 768 + kc * 32 + (l >> 4) * 8;
    float4 a = *(const float4*)src;
    float4 b = *(const float4*)(src + 4);
    short8 o;
    o[0] = f2bf(a.x); o[1] = f2bf(a.y); o[2] = f2bf(a.z); o[3] = f2bf(a.w);
    o[4] = f2bf(b.x); o[5] = f2bf(b.y); o[6] = f2bf(b.z); o[7] = f2bf(b.w);
    *(short8*)(Apk + (size_t)(kc * 788 + mt) * 512 + l * 8) = o;
  } else if (bid < 5880) {
    const bool isq = bid < 5592;
    const float* W = isq ? qkv_w : out_w;
    const float* la = isq ? qkv_la : out_la;
    const float* lb = isq ? qkv_lb : out_lb;
    unsigned short* dst = isq ? Wq : Wo;
    const int NRT = isq ? 144 : 48;
    const int base = isq ? 4728 : 5592;
    int wv = ((bid - base) * 256 + t) >> 6;
    int rt = wv / 24, kc = wv - rt * 24;
    int lr = l & 15;
    const int o = rt * 16 + lr;
    const int d0 = kc * 32 + (l >> 4) * 8;
    const float* src = W + (size_t)o * 768 + d0;
    float4 a = *(const float4*)src;
    float4 b = *(const float4*)(src + 4);
    float wvv[8] = {a.x, a.y, a.z, a.w, b.x, b.y, b.z, b.w};
    const float4* lb4 = (const float4*)(lb + (size_t)o * 8);
    float4 p0 = lb4[0], p1 = lb4[1];
    float lbv[8] = {p0.x, p0.y, p0.z, p0.w, p1.x, p1.y, p1.z, p1.w};
#pragma unroll
    for (int r = 0; r < 8; ++r) {
      const float4* la4 = (const float4*)(la + (size_t)r * 768 + d0);
      float4 c = la4[0], dd = la4[1];
      float s = 2.0f * lbv[r];
      wvv[0] += s * c.x;  wvv[1] += s * c.y;  wvv[2] += s * c.z;  wvv[3] += s * c.w;
      wvv[4] += s * dd.x; wvv[5] += s * dd.y; wvv[6] += s * dd.z; wvv[7] += s * dd.w;
    }
    short8 oo;
#pragma unroll
    for (int e = 0; e < 8; ++e) oo[e] = f2bf(wvv[e]);
    *(short8*)(dst + (size_t)(kc * NRT + rt) * 512 + l * 8) = oo;
  } else {
    int r = (bid - 5880) * 256 + t;  // [0, 49152)
    int bh = r >> 6, hd = r & 63;
    unsigned short* base = Vtpk + (size_t)bh * 14336 + (24 + (hd >> 4)) * 512;  // kc=6 plane
#pragma unroll
    for (int c = 0; c < 27; ++c) {
      int n = 197 + c;
      base[((hd & 15) + 16 * ((n & 31) >> 3)) * 8 + (n & 7)] = 0;
    }
  }
}

// ---------------- GEMM: B via LDS, A reg depth-2, shared-B 4-wave block ----------------
template <int MODE, int NT, int NRTB, int SLOTS, int OCC>
__global__ __launch_bounds__(256, OCC) void k_gp4(
    const unsigned short* __restrict__ Apk, const unsigned short* __restrict__ Bpk,
    const float* __restrict__ bias, unsigned short* __restrict__ Qpk,
    unsigned short* __restrict__ Kpk, unsigned short* __restrict__ Vtpk,
    float* __restrict__ outp) {
  __shared__ __align__(16) char bl[SLOTS * 4096];
  const int w = threadIdx.x >> 6, l = threadIdx.x & 63;
  const int lr = l & 15, lg = l >> 4;
  const int nwg = gridDim.x;
  const int orig = blockIdx.x;
  const int qq = nwg >> 3, rr = nwg & 7, xcd = orig & 7;
  const int wgid = (xcd < rr ? xcd * (qq + 1) : rr * (qq + 1) + (xcd - rr) * qq) + (orig >> 3);
  const int mg = wgid / NT, nt = wgid - mg * NT;
  int mtw = mg * 4 + w;
  if (mtw > 196) mtw = 196;
  const int m0 = mtw * 64, n0 = nt * 64;

  const size_t KSA = 788 * 512;
  const unsigned short* pa = Apk + (size_t)(mtw * 4) * 512 + l * 8;

  auto* lds3 = (__attribute__((address_space(3))) char*)bl;
  auto STB = [&](int kc) {
    const unsigned short* g = Bpk + ((size_t)kc * NRTB + nt * 4 + w) * 512 + l * 8;
    __builtin_amdgcn_global_load_lds((const __attribute__((address_space(1))) void*)g,
                                     (__attribute__((address_space(3))) void*)(lds3 + ((kc % SLOTS) * 4 + w) * 1024),
                                     16, 0, 0);
  };

  f32x4 acc[4][4];
#pragma unroll
  for (int i = 0; i < 4; ++i)
#pragma unroll
    for (int j = 0; j < 4; ++j) acc[i][j] = (f32x4){0.f, 0.f, 0.f, 0.f};

  short8 ab[2][4];
#define LDA4(dst, kt) \
  { const unsigned short* q_ = pa + (size_t)(kt) * KSA; \
    dst[0] = *(const short8*)(q_); dst[1] = *(const short8*)(q_ + 512); \
    dst[2] = *(const short8*)(q_ + 1024); dst[3] = *(const short8*)(q_ + 1536); }

#pragma unroll
  for (int kc = 0; kc < SLOTS; ++kc) STB(kc);
  asm volatile("s_waitcnt vmcnt(0)" ::: "memory");
  SB;
  __builtin_amdgcn_s_barrier();
  LDA4(ab[0], 0);
  LDA4(ab[1], 1);

#pragma unroll
  for (int kt = 0; kt < 24; ++kt) {
    if (kt != 0 && (kt % SLOTS) == 0) {
      asm volatile("s_waitcnt vmcnt(4)" ::: "memory");
      SB;
      __builtin_amdgcn_s_barrier();
    }
    short8 bfr[4];
    const char* sbase = (const char*)bl + (kt % SLOTS) * 4096;
#pragma unroll
    for (int nf = 0; nf < 4; ++nf)
      bfr[nf] = *(const short8*)(sbase + nf * 1024 + l * 16);
    if ((kt % SLOTS) == SLOTS - 1 && kt < 23) {
      asm volatile("s_waitcnt lgkmcnt(0)" ::: "memory");
      SB;
      __builtin_amdgcn_s_barrier();
#pragma unroll
      for (int kc2 = 1; kc2 <= SLOTS; ++kc2)
        if (kt + kc2 < 24) STB(kt + kc2);
    }
    __builtin_amdgcn_s_setprio(1);
#pragma unroll
    for (int mf = 0; mf < 4; ++mf)
#pragma unroll
      for (int nf = 0; nf < 4; ++nf)
        acc[mf][nf] = __builtin_amdgcn_mfma_f32_16x16x32_bf16(ab[kt & 1][mf], bfr[nf], acc[mf][nf], 0, 0, 0);
    __builtin_amdgcn_s_setprio(0);
    if (kt + 2 < 24) LDA4(ab[kt & 1], kt + 2);
  }
#undef LDA4

  float bo[4];
#pragma unroll
  for (int nf = 0; nf < 4; ++nf) bo[nf] = bias[n0 + nf * 16 + lr];
  const int which = nt / 12;
  const int hh = nt - which * 12;
#pragma unroll
  for (int mf = 0; mf < 4; ++mf) {
#pragma unroll
    for (int v = 0; v < 4; ++v) {
      int m = m0 + mf * 16 + lg * 4 + v;
      int b = m / 197;
      int n = m - b * 197;
#pragma unroll
      for (int nf = 0; nf < 4; ++nf) {
        float val = acc[mf][nf][v] + bo[nf];
        if (MODE == 0) {
          int bh = b * 12 + hh;
          unsigned short hv = f2bf(val);
          if (which == 2) {
            Vtpk[(size_t)bh * 14336 + ((n >> 5) * 4 + nf) * 512 +
                 (lr + 16 * ((n & 31) >> 3)) * 8 + (n & 7)] = hv;
          } else {
            unsigned short* dst = (which == 0) ? Qpk : Kpk;
            dst[(size_t)bh * 14336 + ((nf >> 1) * 14 + (n >> 4)) * 512 +
                ((n & 15) + 16 * ((nf & 1) * 2 + (lr >> 3))) * 8 + (lr & 7)] = hv;
          }
        } else {
          outp[(size_t)m * 768 + n0 + nf * 16 + lr] = val;
        }
      }
    }
  }
}

// ---------------- attention: block per (b,h), K+V staged, chunked P (2KB/wave) ----------------
// LDS = 28(K) + 28(V) + 16(P dbuf) = 72KB -> 2 blocks/CU (16 waves/CU).
__global__ __launch_bounds__(512) void k_attn_c(const unsigned short* __restrict__ Qpk,
                                                const unsigned short* __restrict__ Kpk,
                                                const unsigned short* __restrict__ Vtpk,
                                                unsigned short* __restrict__ Apk) {
  __shared__ __align__(16) unsigned short Ks[14336];
  __shared__ __align__(16) unsigned short Vs[14336];
  __shared__ __align__(16) unsigned short Pb[8][2][512];
  const int w = threadIdx.x >> 6, l = threadIdx.x & 63;
  const int lr = l & 15, lg = l >> 4;
  // bijective XCD swizzle (nwg = 768, divisible by 8)
  const int nwg = gridDim.x;
  const int orig = blockIdx.x;
  const int qq = nwg >> 3, xcd = orig & 7;
  const int bh = xcd * qq + (orig >> 3);
  const int b = bh / 12, h = bh - b * 12;
  const unsigned short* Qb = Qpk + (size_t)bh * 14336;
  const unsigned short* Kb = Kpk + (size_t)bh * 14336;
  const unsigned short* Vb = Vtpk + (size_t)bh * 14336;

  // stage K and V planes into LDS (28 chunks of 1KB each; wave-contiguous)
  auto* ldsK = (__attribute__((address_space(3))) char*)Ks;
  auto* ldsV = (__attribute__((address_space(3))) char*)Vs;
  for (int c = w; c < 28; c += 8) {
    __builtin_amdgcn_global_load_lds((const __attribute__((address_space(1))) void*)(Kb + c * 512 + l * 8),
                                     (__attribute__((address_space(3))) void*)(ldsK + c * 1024), 16, 0, 0);
    __builtin_amdgcn_global_load_lds((const __attribute__((address_space(1))) void*)(Vb + c * 512 + l * 8),
                                     (__attribute__((address_space(3))) void*)(ldsV + c * 1024), 16, 0, 0);
  }
  asm volatile("s_waitcnt vmcnt(0)" ::: "memory");
  SB;
  __builtin_amdgcn_s_barrier();

  for (int t = w; t < 13; t += 8) {
    short8 aq0 = *(const short8*)(Qb + (size_t)t * 512 + l * 8);
    short8 aq1 = *(const short8*)(Qb + (size_t)(14 + t) * 512 + l * 8);
    f32x4 s[13];
#pragma unroll
    for (int jt = 0; jt < 13; ++jt) {  // jt=13 is all-pad: skipped, P=0
      f32x4 a = (f32x4){0.f, 0.f, 0.f, 0.f};
      short8 bk0 = *(const short8*)(Ks + (size_t)jt * 512 + l * 8);
      short8 bk1 = *(const short8*)(Ks + (size_t)(14 + jt) * 512 + l * 8);
      __builtin_amdgcn_s_setprio(1);
      a = __builtin_amdgcn_mfma_f32_16x16x32_bf16(aq0, bk0, a, 0, 0, 0);
      a = __builtin_amdgcn_mfma_f32_16x16x32_bf16(aq1, bk1, a, 0, 0, 0);
      __builtin_amdgcn_s_setprio(0);
      s[jt] = a;
    }
#pragma unroll
    for (int v = 0; v < 4; ++v)
      if (lr >= 5) s[12][v] = -1.0e30f;
    float mx[4] = {-3.0e38f, -3.0e38f, -3.0e38f, -3.0e38f};
#pragma unroll
    for (int jt = 0; jt < 13; ++jt)
#pragma unroll
      for (int v = 0; v < 4; ++v) mx[v] = fmaxf(mx[v], s[jt][v]);
#pragma unroll
    for (int v = 0; v < 4; ++v) {
      mx[v] = fmaxf(mx[v], __shfl_xor(mx[v], 1));
      mx[v] = fmaxf(mx[v], __shfl_xor(mx[v], 2));
      mx[v] = fmaxf(mx[v], __shfl_xor(mx[v], 4));
      mx[v] = fmaxf(mx[v], __shfl_xor(mx[v], 8));
    }
    float sum[4] = {0.f, 0.f, 0.f, 0.f};
    const float cc = 0.125f * 1.44269504088896341f;
#pragma unroll
    for (int jt = 0; jt < 13; ++jt)
#pragma unroll
      for (int v = 0; v < 4; ++v) {
        float pv = exp2f((s[jt][v] - mx[v]) * cc);
        s[jt][v] = pv;
        sum[v] += pv;
      }
#pragma unroll
    for (int v = 0; v < 4; ++v) {
      sum[v] += __shfl_xor(sum[v], 1);
      sum[v] += __shfl_xor(sum[v], 2);
      sum[v] += __shfl_xor(sum[v], 4);
      sum[v] += __shfl_xor(sum[v], 8);
    }
    float inv[4];
#pragma unroll
    for (int v = 0; v < 4; ++v) inv[v] = 1.0f / sum[v];
    // PV with chunked P: per kk write 2 jt slices into a 1KB dbuf, read frag, MFMA
    f32x4 oacc[4];
#pragma unroll
    for (int jo = 0; jo < 4; ++jo) oacc[jo] = (f32x4){0.f, 0.f, 0.f, 0.f};
#pragma unroll
    for (int kk = 0; kk < 7; ++kk) {
      unsigned short* pw = &Pb[w][kk & 1][0];
#pragma unroll
      for (int jh = 0; jh < 2; ++jh) {
        const int jt = 2 * kk + jh;
        const int base = (jh * 2 + (lr >> 3)) * 128 + (lr & 7);
        if (jt < 13) {
#pragma unroll
          for (int v = 0; v < 4; ++v)
            pw[base + (lg * 4 + v) * 8] = f2bf(s[jt][v] * inv[v]);
        } else {
#pragma unroll
          for (int v = 0; v < 4; ++v) pw[base + (lg * 4 + v) * 8] = 0;
        }
      }
      short8 pa = *(const short8*)(pw + l * 8);
      __builtin_amdgcn_s_setprio(1);
#pragma unroll
      for (int jo = 0; jo < 4; ++jo) {
        short8 bv = *(const short8*)(Vs + (size_t)(kk * 4 + jo) * 512 + l * 8);
        oacc[jo] = __builtin_amdgcn_mfma_f32_16x16x32_bf16(pa, bv, oacc[jo], 0, 0, 0);
      }
      __builtin_amdgcn_s_setprio(0);
    }
    const int q0 = t * 16;
#pragma unroll
    for (int jo = 0; jo < 4; ++jo) {
      const int kc = h * 2 + (jo >> 1);
      const int lgp = (jo & 1) * 2 + (lr >> 3);
      const int e = lr & 7;
#pragma unroll
      for (int v = 0; v < 4; ++v) {
        int n = q0 + lg * 4 + v;
        if (n < 197) {
          int m = b * 197 + n;
          Apk[((size_t)(kc * 788 + (m >> 4)) * 64 + (m & 15) + 16 * lgp) * 8 + e] = f2bf(oacc[jo][v]);
        }
      }
    }
  }
}

extern "C" void kernel_launch(void* const* d_in, const int* in_sizes, int n_in,
                              void* d_out, int out_size, void* d_ws, size_t ws_size,
                              hipStream_t stream) {
  const float* x      = (const float*)d_in[0];
  const float* qkv_w  = (const float*)d_in[1];
  const float* qkv_b  = (const float*)d_in[2];
  const float* qkv_la = (const float*)d_in[3];
  const float* qkv_lb = (const float*)d_in[4];
  const float* out_w  = (const float*)d_in[5];
  const float* out_b  = (const float*)d_in[6];
  const float* out_la = (const float*)d_in[7];
  const float* out_lb = (const float*)d_in[8];
  float* out = (float*)d_out;

  char* p = (char*)d_ws;
  auto carve = [&](size_t bytes) {
    char* r = p;
    p += (bytes + 255) & ~(size_t)255;
    return r;
  };
  unsigned short* Apk  = (unsigned short*)carve((size_t)788 * 24 * 512 * 2 + 32768);
  unsigned short* Wqpk = (unsigned short*)carve((size_t)144 * 24 * 512 * 2);
  unsigned short* Wopk = (unsigned short*)carve((size_t)48 * 24 * 512 * 2);
  unsigned short* Qpk  = (unsigned short*)carve((size_t)768 * 14336 * 2);
  unsigned short* Kpk  = (unsigned short*)carve((size_t)768 * 14336 * 2);
  unsigned short* Vtpk = (unsigned short*)carve((size_t)768 * 14336 * 2);

  // prep: 4728 (x-pack) + 864 (qkv_w fold) + 288 (out_w fold) + 192 (V pads)
  k_prep4<<<6072, 256, 0, stream>>>(x, qkv_w, out_w, qkv_la, qkv_lb, out_la, out_lb,
                                    Apk, Wqpk, Wopk, Vtpk);
  // qkv: 50 mg x 36 nt; 8-slot LDS, 4 blocks/CU
  k_gp4<0, 36, 144, 8, 4><<<50 * 36, 256, 0, stream>>>(Apk, Wqpk, qkv_b, Qpk, Kpk, Vtpk, nullptr);
  // attention: block per (b,h), K+V staged, chunked P (72KB LDS -> 2 blocks/CU)
  k_attn_c<<<768, 512, 0, stream>>>(Qpk, Kpk, Vtpk, Apk);  // Apk now holds packed attn-out
  // out: 50 mg x 12 nt; 8-slot LDS, 4 blocks/CU
  k_gp4<1, 12, 48, 8, 4><<<50 * 12, 256, 0, stream>>>(Apk, Wopk, out_b, nullptr, nullptr, nullptr, out);
}

// Round 21
// 140.860 us; speedup vs baseline: 1.0851x; 1.0004x over previous
//
#include <hip/hip_runtime.h>
#include <stdint.h>

typedef __attribute__((ext_vector_type(8))) short short8;
typedef __attribute__((ext_vector_type(4))) float f32x4;

#define SB __builtin_amdgcn_sched_barrier(0)

__device__ __forceinline__ unsigned short f2bf(float f) {
  unsigned u = __float_as_uint(f);
  u += 0x7FFF + ((u >> 16) & 1);
  return (unsigned short)(u >> 16);
}

// Packed fragment layout (k-major) for mfma_f32_16x16x32_bf16 operands:
// frag tile (rt, kc): short off = (kc*NRT + rt)*512 + L*8 + e,
// L = (row&15) + 16*((k&31)>>3), e = k&7. 1 frag = wave-contiguous 1KB.
// Per-head planes (28KB = 14336 shorts): Q/K: 14 rt (n) x 2 kc (d);
// Vt: 4 rt (d) x 7 kc (n), tile index kc*4+rt.

// ---------------- merged prep (parallel, barrier-free x-pack) ----------------
__global__ __launch_bounds__(256) void k_prep4(const float* __restrict__ x,
                                               const float* __restrict__ qkv_w,
                                               const float* __restrict__ out_w,
                                               const float* __restrict__ qkv_la,
                                               const float* __restrict__ qkv_lb,
                                               const float* __restrict__ out_la,
                                               const float* __restrict__ out_lb,
                                               unsigned short* __restrict__ Apk,
                                               unsigned short* __restrict__ Wq,
                                               unsigned short* __restrict__ Wo,
                                               unsigned short* __restrict__ Vtpk) {
  const int bid = blockIdx.x;
  const int t = threadIdx.x;
  const int w = t >> 6, l = t & 63;
  if (bid < 4728) {
    const int task = bid * 4 + w;           // [0, 18912)
    const int mt = task / 24, kc = task - mt * 24;
    const float* src = x + (size_t)(mt * 16 + (l & 15)) * 768 + kc * 32 + (l >> 4) * 8;
    float4 a = *(const float4*)src;
    float4 b = *(const float4*)(src + 4);
    short8 o;
    o[0] = f2bf(a.x); o[1] = f2bf(a.y); o[2] = f2bf(a.z); o[3] = f2bf(a.w);
    o[4] = f2bf(b.x); o[5] = f2bf(b.y); o[6] = f2bf(b.z); o[7] = f2bf(b.w);
    *(short8*)(Apk + (size_t)(kc * 788 + mt) * 512 + l * 8) = o;
  } else if (bid < 5880) {
    const bool isq = bid < 5592;
    const float* W = isq ? qkv_w : out_w;
    const float* la = isq ? qkv_la : out_la;
    const float* lb = isq ? qkv_lb : out_lb;
    unsigned short* dst = isq ? Wq : Wo;
    const int NRT = isq ? 144 : 48;
    const int base = isq ? 4728 : 5592;
    int wv = ((bid - base) * 256 + t) >> 6;
    int rt = wv / 24, kc = wv - rt * 24;
    int lr = l & 15;
    const int o = rt * 16 + lr;
    const int d0 = kc * 32 + (l >> 4) * 8;
    const float* src = W + (size_t)o * 768 + d0;
    float4 a = *(const float4*)src;
    float4 b = *(const float4*)(src + 4);
    float wvv[8] = {a.x, a.y, a.z, a.w, b.x, b.y, b.z, b.w};
    const float4* lb4 = (const float4*)(lb + (size_t)o * 8);
    float4 p0 = lb4[0], p1 = lb4[1];
    float lbv[8] = {p0.x, p0.y, p0.z, p0.w, p1.x, p1.y, p1.z, p1.w};
#pragma unroll
    for (int r = 0; r < 8; ++r) {
      const float4* la4 = (const float4*)(la + (size_t)r * 768 + d0);
      float4 c = la4[0], dd = la4[1];
      float s = 2.0f * lbv[r];
      wvv[0] += s * c.x;  wvv[1] += s * c.y;  wvv[2] += s * c.z;  wvv[3] += s * c.w;
      wvv[4] += s * dd.x; wvv[5] += s * dd.y; wvv[6] += s * dd.z; wvv[7] += s * dd.w;
    }
    short8 oo;
#pragma unroll
    for (int e = 0; e < 8; ++e) oo[e] = f2bf(wvv[e]);
    *(short8*)(dst + (size_t)(kc * NRT + rt) * 512 + l * 8) = oo;
  } else {
    int r = (bid - 5880) * 256 + t;  // [0, 49152)
    int bh = r >> 6, hd = r & 63;
    unsigned short* base = Vtpk + (size_t)bh * 14336 + (24 + (hd >> 4)) * 512;  // kc=6 plane
#pragma unroll
    for (int c = 0; c < 27; ++c) {
      int n = 197 + c;
      base[((hd & 15) + 16 * ((n & 31) >> 3)) * 8 + (n & 7)] = 0;
    }
  }
}

// ---------------- GEMM: B via LDS, A reg depth-2, shared-B 4-wave block ----------------
template <int MODE, int NT, int NRTB, int SLOTS, int OCC>
__global__ __launch_bounds__(256, OCC) void k_gp4(
    const unsigned short* __restrict__ Apk, const unsigned short* __restrict__ Bpk,
    const float* __restrict__ bias, unsigned short* __restrict__ Qpk,
    unsigned short* __restrict__ Kpk, unsigned short* __restrict__ Vtpk,
    float* __restrict__ outp) {
  __shared__ __align__(16) char bl[SLOTS * 4096];
  const int w = threadIdx.x >> 6, l = threadIdx.x & 63;
  const int lr = l & 15, lg = l >> 4;
  const int nwg = gridDim.x;
  const int orig = blockIdx.x;
  const int qq = nwg >> 3, rr = nwg & 7, xcd = orig & 7;
  const int wgid = (xcd < rr ? xcd * (qq + 1) : rr * (qq + 1) + (xcd - rr) * qq) + (orig >> 3);
  const int mg = wgid / NT, nt = wgid - mg * NT;
  int mtw = mg * 4 + w;
  if (mtw > 196) mtw = 196;
  const int m0 = mtw * 64, n0 = nt * 64;

  const size_t KSA = 788 * 512;
  const unsigned short* pa = Apk + (size_t)(mtw * 4) * 512 + l * 8;

  auto* lds3 = (__attribute__((address_space(3))) char*)bl;
  auto STB = [&](int kc) {
    const unsigned short* g = Bpk + ((size_t)kc * NRTB + nt * 4 + w) * 512 + l * 8;
    __builtin_amdgcn_global_load_lds((const __attribute__((address_space(1))) void*)g,
                                     (__attribute__((address_space(3))) void*)(lds3 + ((kc % SLOTS) * 4 + w) * 1024),
                                     16, 0, 0);
  };

  f32x4 acc[4][4];
#pragma unroll
  for (int i = 0; i < 4; ++i)
#pragma unroll
    for (int j = 0; j < 4; ++j) acc[i][j] = (f32x4){0.f, 0.f, 0.f, 0.f};

  short8 ab[2][4];
#define LDA4(dst, kt) \
  { const unsigned short* q_ = pa + (size_t)(kt) * KSA; \
    dst[0] = *(const short8*)(q_); dst[1] = *(const short8*)(q_ + 512); \
    dst[2] = *(const short8*)(q_ + 1024); dst[3] = *(const short8*)(q_ + 1536); }

#pragma unroll
  for (int kc = 0; kc < SLOTS; ++kc) STB(kc);
  asm volatile("s_waitcnt vmcnt(0)" ::: "memory");
  SB;
  __builtin_amdgcn_s_barrier();
  LDA4(ab[0], 0);
  LDA4(ab[1], 1);

#pragma unroll
  for (int kt = 0; kt < 24; ++kt) {
    if (kt != 0 && (kt % SLOTS) == 0) {
      asm volatile("s_waitcnt vmcnt(4)" ::: "memory");
      SB;
      __builtin_amdgcn_s_barrier();
    }
    short8 bfr[4];
    const char* sbase = (const char*)bl + (kt % SLOTS) * 4096;
#pragma unroll
    for (int nf = 0; nf < 4; ++nf)
      bfr[nf] = *(const short8*)(sbase + nf * 1024 + l * 16);
    if ((kt % SLOTS) == SLOTS - 1 && kt < 23) {
      asm volatile("s_waitcnt lgkmcnt(0)" ::: "memory");
      SB;
      __builtin_amdgcn_s_barrier();
#pragma unroll
      for (int kc2 = 1; kc2 <= SLOTS; ++kc2)
        if (kt + kc2 < 24) STB(kt + kc2);
    }
    __builtin_amdgcn_s_setprio(1);
#pragma unroll
    for (int mf = 0; mf < 4; ++mf)
#pragma unroll
      for (int nf = 0; nf < 4; ++nf)
        acc[mf][nf] = __builtin_amdgcn_mfma_f32_16x16x32_bf16(ab[kt & 1][mf], bfr[nf], acc[mf][nf], 0, 0, 0);
    __builtin_amdgcn_s_setprio(0);
    if (kt + 2 < 24) LDA4(ab[kt & 1], kt + 2);
  }
#undef LDA4

  float bo[4];
#pragma unroll
  for (int nf = 0; nf < 4; ++nf) bo[nf] = bias[n0 + nf * 16 + lr];
  const int which = nt / 12;
  const int hh = nt - which * 12;
#pragma unroll
  for (int mf = 0; mf < 4; ++mf) {
#pragma unroll
    for (int v = 0; v < 4; ++v) {
      int m = m0 + mf * 16 + lg * 4 + v;
      int b = m / 197;
      int n = m - b * 197;
#pragma unroll
      for (int nf = 0; nf < 4; ++nf) {
        float val = acc[mf][nf][v] + bo[nf];
        if (MODE == 0) {
          int bh = b * 12 + hh;
          unsigned short hv = f2bf(val);
          if (which == 2) {
            Vtpk[(size_t)bh * 14336 + ((n >> 5) * 4 + nf) * 512 +
                 (lr + 16 * ((n & 31) >> 3)) * 8 + (n & 7)] = hv;
          } else {
            unsigned short* dst = (which == 0) ? Qpk : Kpk;
            dst[(size_t)bh * 14336 + ((nf >> 1) * 14 + (n >> 4)) * 512 +
                ((n & 15) + 16 * ((nf & 1) * 2 + (lr >> 3))) * 8 + (lr & 7)] = hv;
          }
        } else {
          outp[(size_t)m * 768 + n0 + nf * 16 + lr] = val;
        }
      }
    }
  }
}

// ---------------- attention: block per (b,h), K+V staged, chunked P (2KB/wave) ----------------
// LDS = 28(K) + 28(V) + 16(P dbuf) = 72KB -> 2 blocks/CU (16 waves/CU).
__global__ __launch_bounds__(512) void k_attn_c(const unsigned short* __restrict__ Qpk,
                                                const unsigned short* __restrict__ Kpk,
                                                const unsigned short* __restrict__ Vtpk,
                                                unsigned short* __restrict__ Apk) {
  __shared__ __align__(16) unsigned short Ks[14336];
  __shared__ __align__(16) unsigned short Vs[14336];
  __shared__ __align__(16) unsigned short Pb[8][2][512];
  const int w = threadIdx.x >> 6, l = threadIdx.x & 63;
  const int lr = l & 15, lg = l >> 4;
  // bijective XCD swizzle (nwg = 768, divisible by 8)
  const int nwg = gridDim.x;
  const int orig = blockIdx.x;
  const int qq = nwg >> 3, xcd = orig & 7;
  const int bh = xcd * qq + (orig >> 3);
  const int b = bh / 12, h = bh - b * 12;
  const unsigned short* Qb = Qpk + (size_t)bh * 14336;
  const unsigned short* Kb = Kpk + (size_t)bh * 14336;
  const unsigned short* Vb = Vtpk + (size_t)bh * 14336;

  // stage K and V planes into LDS (28 chunks of 1KB each; wave-contiguous)
  auto* ldsK = (__attribute__((address_space(3))) char*)Ks;
  auto* ldsV = (__attribute__((address_space(3))) char*)Vs;
  for (int c = w; c < 28; c += 8) {
    __builtin_amdgcn_global_load_lds((const __attribute__((address_space(1))) void*)(Kb + c * 512 + l * 8),
                                     (__attribute__((address_space(3))) void*)(ldsK + c * 1024), 16, 0, 0);
    __builtin_amdgcn_global_load_lds((const __attribute__((address_space(1))) void*)(Vb + c * 512 + l * 8),
                                     (__attribute__((address_space(3))) void*)(ldsV + c * 1024), 16, 0, 0);
  }
  asm volatile("s_waitcnt vmcnt(0)" ::: "memory");
  SB;
  __builtin_amdgcn_s_barrier();

  for (int t = w; t < 13; t += 8) {
    short8 aq0 = *(const short8*)(Qb + (size_t)t * 512 + l * 8);
    short8 aq1 = *(const short8*)(Qb + (size_t)(14 + t) * 512 + l * 8);
    f32x4 s[13];
#pragma unroll
    for (int jt = 0; jt < 13; ++jt) {  // jt=13 is all-pad: skipped, P=0
      f32x4 a = (f32x4){0.f, 0.f, 0.f, 0.f};
      short8 bk0 = *(const short8*)(Ks + (size_t)jt * 512 + l * 8);
      short8 bk1 = *(const short8*)(Ks + (size_t)(14 + jt) * 512 + l * 8);
      __builtin_amdgcn_s_setprio(1);
      a = __builtin_amdgcn_mfma_f32_16x16x32_bf16(aq0, bk0, a, 0, 0, 0);
      a = __builtin_amdgcn_mfma_f32_16x16x32_bf16(aq1, bk1, a, 0, 0, 0);
      __builtin_amdgcn_s_setprio(0);
      s[jt] = a;
    }
#pragma unroll
    for (int v = 0; v < 4; ++v)
      if (lr >= 5) s[12][v] = -1.0e30f;
    float mx[4] = {-3.0e38f, -3.0e38f, -3.0e38f, -3.0e38f};
#pragma unroll
    for (int jt = 0; jt < 13; ++jt)
#pragma unroll
      for (int v = 0; v < 4; ++v) mx[v] = fmaxf(mx[v], s[jt][v]);
#pragma unroll
    for (int v = 0; v < 4; ++v) {
      mx[v] = fmaxf(mx[v], __shfl_xor(mx[v], 1));
      mx[v] = fmaxf(mx[v], __shfl_xor(mx[v], 2));
      mx[v] = fmaxf(mx[v], __shfl_xor(mx[v], 4));
      mx[v] = fmaxf(mx[v], __shfl_xor(mx[v], 8));
    }
    float sum[4] = {0.f, 0.f, 0.f, 0.f};
    const float cc = 0.125f * 1.44269504088896341f;
#pragma unroll
    for (int jt = 0; jt < 13; ++jt)
#pragma unroll
      for (int v = 0; v < 4; ++v) {
        float pv = exp2f((s[jt][v] - mx[v]) * cc);
        s[jt][v] = pv;
        sum[v] += pv;
      }
#pragma unroll
    for (int v = 0; v < 4; ++v) {
      sum[v] += __shfl_xor(sum[v], 1);
      sum[v] += __shfl_xor(sum[v], 2);
      sum[v] += __shfl_xor(sum[v], 4);
      sum[v] += __shfl_xor(sum[v], 8);
    }
    float inv[4];
#pragma unroll
    for (int v = 0; v < 4; ++v) inv[v] = 1.0f / sum[v];
    // PV with chunked P: per kk write 2 jt slices into a 1KB dbuf, read frag, MFMA
    f32x4 oacc[4];
#pragma unroll
    for (int jo = 0; jo < 4; ++jo) oacc[jo] = (f32x4){0.f, 0.f, 0.f, 0.f};
#pragma unroll
    for (int kk = 0; kk < 7; ++kk) {
      unsigned short* pw = &Pb[w][kk & 1][0];
#pragma unroll
      for (int jh = 0; jh < 2; ++jh) {
        const int jt = 2 * kk + jh;
        const int base = (jh * 2 + (lr >> 3)) * 128 + (lr & 7);
        if (jt < 13) {
#pragma unroll
          for (int v = 0; v < 4; ++v)
            pw[base + (lg * 4 + v) * 8] = f2bf(s[jt][v] * inv[v]);
        } else {
#pragma unroll
          for (int v = 0; v < 4; ++v) pw[base + (lg * 4 + v) * 8] = 0;
        }
      }
      short8 pa = *(const short8*)(pw + l * 8);
      __builtin_amdgcn_s_setprio(1);
#pragma unroll
      for (int jo = 0; jo < 4; ++jo) {
        short8 bv = *(const short8*)(Vs + (size_t)(kk * 4 + jo) * 512 + l * 8);
        oacc[jo] = __builtin_amdgcn_mfma_f32_16x16x32_bf16(pa, bv, oacc[jo], 0, 0, 0);
      }
      __builtin_amdgcn_s_setprio(0);
    }
    const int q0 = t * 16;
#pragma unroll
    for (int jo = 0; jo < 4; ++jo) {
      const int kc = h * 2 + (jo >> 1);
      const int lgp = (jo & 1) * 2 + (lr >> 3);
      const int e = lr & 7;
#pragma unroll
      for (int v = 0; v < 4; ++v) {
        int n = q0 + lg * 4 + v;
        if (n < 197) {
          int m = b * 197 + n;
          Apk[((size_t)(kc * 788 + (m >> 4)) * 64 + (m & 15) + 16 * lgp) * 8 + e] = f2bf(oacc[jo][v]);
        }
      }
    }
  }
}

extern "C" void kernel_launch(void* const* d_in, const int* in_sizes, int n_in,
                              void* d_out, int out_size, void* d_ws, size_t ws_size,
                              hipStream_t stream) {
  const float* x      = (const float*)d_in[0];
  const float* qkv_w  = (const float*)d_in[1];
  const float* qkv_b  = (const float*)d_in[2];
  const float* qkv_la = (const float*)d_in[3];
  const float* qkv_lb = (const float*)d_in[4];
  const float* out_w  = (const float*)d_in[5];
  const float* out_b  = (const float*)d_in[6];
  const float* out_la = (const float*)d_in[7];
  const float* out_lb = (const float*)d_in[8];
  float* out = (float*)d_out;

  char* p = (char*)d_ws;
  auto carve = [&](size_t bytes) {
    char* r = p;
    p += (bytes + 255) & ~(size_t)255;
    return r;
  };
  unsigned short* Apk  = (unsigned short*)carve((size_t)788 * 24 * 512 * 2 + 32768);
  unsigned short* Wqpk = (unsigned short*)carve((size_t)144 * 24 * 512 * 2);
  unsigned short* Wopk = (unsigned short*)carve((size_t)48 * 24 * 512 * 2);
  unsigned short* Qpk  = (unsigned short*)carve((size_t)768 * 14336 * 2);
  unsigned short* Kpk  = (unsigned short*)carve((size_t)768 * 14336 * 2);
  unsigned short* Vtpk = (unsigned short*)carve((size_t)768 * 14336 * 2);

  // prep: 4728 (x-pack) + 864 (qkv_w fold) + 288 (out_w fold) + 192 (V pads)
  k_prep4<<<6072, 256, 0, stream>>>(x, qkv_w, out_w, qkv_la, qkv_lb, out_la, out_lb,
                                    Apk, Wqpk, Wopk, Vtpk);
  // qkv: 50 mg x 36 nt; 8-slot LDS, 4 blocks/CU
  k_gp4<0, 36, 144, 8, 4><<<50 * 36, 256, 0, stream>>>(Apk, Wqpk, qkv_b, Qpk, Kpk, Vtpk, nullptr);
  // attention: block per (b,h), K+V staged, chunked P (72KB LDS -> 2 blocks/CU)
  k_attn_c<<<768, 512, 0, stream>>>(Qpk, Kpk, Vtpk, Apk);  // Apk now holds packed attn-out
  // out: 50 mg x 12 nt; 8-slot LDS, 4 blocks/CU
  k_gp4<1, 12, 48, 8, 4><<<50 * 12, 256, 0, stream>>>(Apk, Wopk, out_b, nullptr, nullptr, nullptr, out);
}

// Round 22
// 137.530 us; speedup vs baseline: 1.1114x; 1.0242x over previous
//
#include <hip/hip_runtime.h>
#include <stdint.h>

typedef __attribute__((ext_vector_type(8))) short short8;
typedef __attribute__((ext_vector_type(4))) float f32x4;

#define SB __builtin_amdgcn_sched_barrier(0)

__device__ __forceinline__ unsigned short f2bf(float f) {
  unsigned u = __float_as_uint(f);
  u += 0x7FFF + ((u >> 16) & 1);
  return (unsigned short)(u >> 16);
}

// Packed fragment layout (k-major) for mfma_f32_16x16x32_bf16 operands:
// frag tile (rt, kc): short off = (kc*NRT + rt)*512 + L*8 + e,
// L = (row&15) + 16*((k&31)>>3), e = k&7. 1 frag = wave-contiguous 1KB.
// Per-head planes (28KB = 14336 shorts): Q/K: 14 rt (n) x 2 kc (d);
// Vt: 4 rt (d) x 7 kc (n), tile index kc*4+rt.

// ---------------- merged prep (parallel, barrier-free x-pack) ----------------
__global__ __launch_bounds__(256) void k_prep4(const float* __restrict__ x,
                                               const float* __restrict__ qkv_w,
                                               const float* __restrict__ out_w,
                                               const float* __restrict__ qkv_la,
                                               const float* __restrict__ qkv_lb,
                                               const float* __restrict__ out_la,
                                               const float* __restrict__ out_lb,
                                               unsigned short* __restrict__ Apk,
                                               unsigned short* __restrict__ Wq,
                                               unsigned short* __restrict__ Wo,
                                               unsigned short* __restrict__ Vtpk) {
  const int bid = blockIdx.x;
  const int t = threadIdx.x;
  const int w = t >> 6, l = t & 63;
  if (bid < 4728) {
    const int task = bid * 4 + w;           // [0, 18912)
    const int mt = task / 24, kc = task - mt * 24;
    const float* src = x + (size_t)(mt * 16 + (l & 15)) * 768 + kc * 32 + (l >> 4) * 8;
    float4 a = *(const float4*)src;
    float4 b = *(const float4*)(src + 4);
    short8 o;
    o[0] = f2bf(a.x); o[1] = f2bf(a.y); o[2] = f2bf(a.z); o[3] = f2bf(a.w);
    o[4] = f2bf(b.x); o[5] = f2bf(b.y); o[6] = f2bf(b.z); o[7] = f2bf(b.w);
    *(short8*)(Apk + (size_t)(kc * 788 + mt) * 512 + l * 8) = o;
  } else if (bid < 5880) {
    const bool isq = bid < 5592;
    const float* W = isq ? qkv_w : out_w;
    const float* la = isq ? qkv_la : out_la;
    const float* lb = isq ? qkv_lb : out_lb;
    unsigned short* dst = isq ? Wq : Wo;
    const int NRT = isq ? 144 : 48;
    const int base = isq ? 4728 : 5592;
    int wv = ((bid - base) * 256 + t) >> 6;
    int rt = wv / 24, kc = wv - rt * 24;
    int lr = l & 15;
    const int o = rt * 16 + lr;
    const int d0 = kc * 32 + (l >> 4) * 8;
    const float* src = W + (size_t)o * 768 + d0;
    float4 a = *(const float4*)src;
    float4 b = *(const float4*)(src + 4);
    float wvv[8] = {a.x, a.y, a.z, a.w, b.x, b.y, b.z, b.w};
    const float4* lb4 = (const float4*)(lb + (size_t)o * 8);
    float4 p0 = lb4[0], p1 = lb4[1];
    float lbv[8] = {p0.x, p0.y, p0.z, p0.w, p1.x, p1.y, p1.z, p1.w};
#pragma unroll
    for (int r = 0; r < 8; ++r) {
      const float4* la4 = (const float4*)(la + (size_t)r * 768 + d0);
      float4 c = la4[0], dd = la4[1];
      float s = 2.0f * lbv[r];
      wvv[0] += s * c.x;  wvv[1] += s * c.y;  wvv[2] += s * c.z;  wvv[3] += s * c.w;
      wvv[4] += s * dd.x; wvv[5] += s * dd.y; wvv[6] += s * dd.z; wvv[7] += s * dd.w;
    }
    short8 oo;
#pragma unroll
    for (int e = 0; e < 8; ++e) oo[e] = f2bf(wvv[e]);
    *(short8*)(dst + (size_t)(kc * NRT + rt) * 512 + l * 8) = oo;
  } else {
    int r = (bid - 5880) * 256 + t;  // [0, 49152)
    int bh = r >> 6, hd = r & 63;
    unsigned short* base = Vtpk + (size_t)bh * 14336 + (24 + (hd >> 4)) * 512;  // kc=6 plane
#pragma unroll
    for (int c = 0; c < 27; ++c) {
      int n = 197 + c;
      base[((hd & 15) + 16 * ((n & 31) >> 3)) * 8 + (n & 7)] = 0;
    }
  }
}

// ---------------- GEMM: B via LDS (8 slots, half-window refill, 5-kt DMA slack) ----------------
// Block = 4 waves: same n-strip, 4 adjacent m-strips. Stage 4 kc-planes at kt=3,7,11,15;
// wait at kt=8,12,16,20 with exact conservative vmcnt (loads fenced by asm memory clobbers).
// MODE 0: qkv (NT=36, NRTB=144) scatter to PACKED Q/K/Vt + bias. MODE 1: out (NT=12, NRTB=48).
template <int MODE, int NT, int NRTB>
__global__ __launch_bounds__(256, 4) void k_gp7(
    const unsigned short* __restrict__ Apk, const unsigned short* __restrict__ Bpk,
    const float* __restrict__ bias, unsigned short* __restrict__ Qpk,
    unsigned short* __restrict__ Kpk, unsigned short* __restrict__ Vtpk,
    float* __restrict__ outp) {
  __shared__ __align__(16) char bl[32768];  // 8 kc-slots x 4 rt x 1KB
  const int w = threadIdx.x >> 6, l = threadIdx.x & 63;
  const int lr = l & 15, lg = l >> 4;
  const int nwg = gridDim.x;
  const int orig = blockIdx.x;
  const int qq = nwg >> 3, rr = nwg & 7, xcd = orig & 7;
  const int wgid = (xcd < rr ? xcd * (qq + 1) : rr * (qq + 1) + (xcd - rr) * qq) + (orig >> 3);
  const int mg = wgid / NT, nt = wgid - mg * NT;
  int mtw = mg * 4 + w;
  if (mtw > 196) mtw = 196;
  const int m0 = mtw * 64, n0 = nt * 64;

  const size_t KSA = 788 * 512;
  const unsigned short* pa = Apk + (size_t)(mtw * 4) * 512 + l * 8;

  auto* lds3 = (__attribute__((address_space(3))) char*)bl;
  auto STB = [&](int kc) {
    const unsigned short* g = Bpk + ((size_t)kc * NRTB + nt * 4 + w) * 512 + l * 8;
    __builtin_amdgcn_global_load_lds((const __attribute__((address_space(1))) void*)g,
                                     (__attribute__((address_space(3))) void*)(lds3 + ((kc & 7) * 4 + w) * 1024),
                                     16, 0, 0);
  };

  f32x4 acc[4][4];
#pragma unroll
  for (int i = 0; i < 4; ++i)
#pragma unroll
    for (int j = 0; j < 4; ++j) acc[i][j] = (f32x4){0.f, 0.f, 0.f, 0.f};

  short8 ab[2][4];
#define LDA4(dst, kt) \
  { const unsigned short* q_ = pa + (size_t)(kt) * KSA; \
    dst[0] = *(const short8*)(q_); dst[1] = *(const short8*)(q_ + 512); \
    dst[2] = *(const short8*)(q_ + 1024); dst[3] = *(const short8*)(q_ + 1536); }

  // prologue: stage kc 0..7, drain, barrier; A kt0/kt1
#pragma unroll
  for (int kc = 0; kc < 8; ++kc) STB(kc);
  asm volatile("s_waitcnt vmcnt(0)" ::: "memory");
  SB;
  __builtin_amdgcn_s_barrier();
  LDA4(ab[0], 0);
  LDA4(ab[1], 1);

#pragma unroll
  for (int kt = 0; kt < 24; ++kt) {
    // wait points: the half-window staged 5 kt earlier must have landed (all waves)
    if (kt >= 8 && (kt & 3) == 0) {
      if (kt == 20) {
        asm volatile("s_waitcnt vmcnt(16)" ::: "memory");  // since stage@15: 16 A-loads
      } else {
        asm volatile("s_waitcnt vmcnt(20)" ::: "memory");  // 16 A-loads + 4 newer stage DMAs
      }
      SB;
      __builtin_amdgcn_s_barrier();
    }
    short8 bfr[4];
    const char* sbase = (const char*)bl + (kt & 7) * 4096;
#pragma unroll
    for (int nf = 0; nf < 4; ++nf)
      bfr[nf] = *(const short8*)(sbase + nf * 1024 + l * 16);
    // stage points: kt=3,7,11,15 stage kc kt+5..kt+8 into the 4 slots just consumed
    if ((kt & 3) == 3 && kt < 16) {
      asm volatile("s_waitcnt lgkmcnt(0)" ::: "memory");  // own reads of overwritten slots done
      SB;
      __builtin_amdgcn_s_barrier();                        // all waves done with those slots
#pragma unroll
      for (int kc2 = 5; kc2 <= 8; ++kc2)
        if (kt + kc2 < 24) STB(kt + kc2);
    }
    __builtin_amdgcn_s_setprio(1);
#pragma unroll
    for (int mf = 0; mf < 4; ++mf)
#pragma unroll
      for (int nf = 0; nf < 4; ++nf)
        acc[mf][nf] = __builtin_amdgcn_mfma_f32_16x16x32_bf16(ab[kt & 1][mf], bfr[nf], acc[mf][nf], 0, 0, 0);
    __builtin_amdgcn_s_setprio(0);
    if (kt + 2 < 24) LDA4(ab[kt & 1], kt + 2);
  }
#undef LDA4

  // epilogue: bias; MODE 0 scatter into PACKED per-head fragment planes
  float bo[4];
#pragma unroll
  for (int nf = 0; nf < 4; ++nf) bo[nf] = bias[n0 + nf * 16 + lr];
  const int which = nt / 12;
  const int hh = nt - which * 12;
#pragma unroll
  for (int mf = 0; mf < 4; ++mf) {
#pragma unroll
    for (int v = 0; v < 4; ++v) {
      int m = m0 + mf * 16 + lg * 4 + v;
      int b = m / 197;
      int n = m - b * 197;
#pragma unroll
      for (int nf = 0; nf < 4; ++nf) {
        float val = acc[mf][nf][v] + bo[nf];
        if (MODE == 0) {
          int bh = b * 12 + hh;
          unsigned short hv = f2bf(val);
          if (which == 2) {
            Vtpk[(size_t)bh * 14336 + ((n >> 5) * 4 + nf) * 512 +
                 (lr + 16 * ((n & 31) >> 3)) * 8 + (n & 7)] = hv;
          } else {
            unsigned short* dst = (which == 0) ? Qpk : Kpk;
            dst[(size_t)bh * 14336 + ((nf >> 1) * 14 + (n >> 4)) * 512 +
                ((n & 15) + 16 * ((nf & 1) * 2 + (lr >> 3))) * 8 + (lr & 7)] = hv;
          }
        } else {
          outp[(size_t)m * 768 + n0 + nf * 16 + lr] = val;
        }
      }
    }
  }
}

// ---------------- attention: block per (b,h), K+V staged, chunked P (2KB/wave) ----------------
// LDS = 28(K) + 28(V) + 16(P dbuf) = 72KB -> 2 blocks/CU (16 waves/CU).
__global__ __launch_bounds__(512) void k_attn_c(const unsigned short* __restrict__ Qpk,
                                                const unsigned short* __restrict__ Kpk,
                                                const unsigned short* __restrict__ Vtpk,
                                                unsigned short* __restrict__ Apk) {
  __shared__ __align__(16) unsigned short Ks[14336];
  __shared__ __align__(16) unsigned short Vs[14336];
  __shared__ __align__(16) unsigned short Pb[8][2][512];
  const int w = threadIdx.x >> 6, l = threadIdx.x & 63;
  const int lr = l & 15, lg = l >> 4;
  const int nwg = gridDim.x;
  const int orig = blockIdx.x;
  const int qq = nwg >> 3, xcd = orig & 7;
  const int bh = xcd * qq + (orig >> 3);
  const int b = bh / 12, h = bh - b * 12;
  const unsigned short* Qb = Qpk + (size_t)bh * 14336;
  const unsigned short* Kb = Kpk + (size_t)bh * 14336;
  const unsigned short* Vb = Vtpk + (size_t)bh * 14336;

  auto* ldsK = (__attribute__((address_space(3))) char*)Ks;
  auto* ldsV = (__attribute__((address_space(3))) char*)Vs;
  for (int c = w; c < 28; c += 8) {
    __builtin_amdgcn_global_load_lds((const __attribute__((address_space(1))) void*)(Kb + c * 512 + l * 8),
                                     (__attribute__((address_space(3))) void*)(ldsK + c * 1024), 16, 0, 0);
    __builtin_amdgcn_global_load_lds((const __attribute__((address_space(1))) void*)(Vb + c * 512 + l * 8),
                                     (__attribute__((address_space(3))) void*)(ldsV + c * 1024), 16, 0, 0);
  }
  asm volatile("s_waitcnt vmcnt(0)" ::: "memory");
  SB;
  __builtin_amdgcn_s_barrier();

  for (int t = w; t < 13; t += 8) {
    short8 aq0 = *(const short8*)(Qb + (size_t)t * 512 + l * 8);
    short8 aq1 = *(const short8*)(Qb + (size_t)(14 + t) * 512 + l * 8);
    f32x4 s[13];
#pragma unroll
    for (int jt = 0; jt < 13; ++jt) {  // jt=13 is all-pad: skipped, P=0
      f32x4 a = (f32x4){0.f, 0.f, 0.f, 0.f};
      short8 bk0 = *(const short8*)(Ks + (size_t)jt * 512 + l * 8);
      short8 bk1 = *(const short8*)(Ks + (size_t)(14 + jt) * 512 + l * 8);
      __builtin_amdgcn_s_setprio(1);
      a = __builtin_amdgcn_mfma_f32_16x16x32_bf16(aq0, bk0, a, 0, 0, 0);
      a = __builtin_amdgcn_mfma_f32_16x16x32_bf16(aq1, bk1, a, 0, 0, 0);
      __builtin_amdgcn_s_setprio(0);
      s[jt] = a;
    }
#pragma unroll
    for (int v = 0; v < 4; ++v)
      if (lr >= 5) s[12][v] = -1.0e30f;
    float mx[4] = {-3.0e38f, -3.0e38f, -3.0e38f, -3.0e38f};
#pragma unroll
    for (int jt = 0; jt < 13; ++jt)
#pragma unroll
      for (int v = 0; v < 4; ++v) mx[v] = fmaxf(mx[v], s[jt][v]);
#pragma unroll
    for (int v = 0; v < 4; ++v) {
      mx[v] = fmaxf(mx[v], __shfl_xor(mx[v], 1));
      mx[v] = fmaxf(mx[v], __shfl_xor(mx[v], 2));
      mx[v] = fmaxf(mx[v], __shfl_xor(mx[v], 4));
      mx[v] = fmaxf(mx[v], __shfl_xor(mx[v], 8));
    }
    float sum[4] = {0.f, 0.f, 0.f, 0.f};
    const float cc = 0.125f * 1.44269504088896341f;
#pragma unroll
    for (int jt = 0; jt < 13; ++jt)
#pragma unroll
      for (int v = 0; v < 4; ++v) {
        float pv = exp2f((s[jt][v] - mx[v]) * cc);
        s[jt][v] = pv;
        sum[v] += pv;
      }
#pragma unroll
    for (int v = 0; v < 4; ++v) {
      sum[v] += __shfl_xor(sum[v], 1);
      sum[v] += __shfl_xor(sum[v], 2);
      sum[v] += __shfl_xor(sum[v], 4);
      sum[v] += __shfl_xor(sum[v], 8);
    }
    float inv[4];
#pragma unroll
    for (int v = 0; v < 4; ++v) inv[v] = 1.0f / sum[v];
    f32x4 oacc[4];
#pragma unroll
    for (int jo = 0; jo < 4; ++jo) oacc[jo] = (f32x4){0.f, 0.f, 0.f, 0.f};
#pragma unroll
    for (int kk = 0; kk < 7; ++kk) {
      unsigned short* pw = &Pb[w][kk & 1][0];
#pragma unroll
      for (int jh = 0; jh < 2; ++jh) {
        const int jt = 2 * kk + jh;
        const int base = (jh * 2 + (lr >> 3)) * 128 + (lr & 7);
        if (jt < 13) {
#pragma unroll
          for (int v = 0; v < 4; ++v)
            pw[base + (lg * 4 + v) * 8] = f2bf(s[jt][v] * inv[v]);
        } else {
#pragma unroll
          for (int v = 0; v < 4; ++v) pw[base + (lg * 4 + v) * 8] = 0;
        }
      }
      short8 pa = *(const short8*)(pw + l * 8);
      __builtin_amdgcn_s_setprio(1);
#pragma unroll
      for (int jo = 0; jo < 4; ++jo) {
        short8 bv = *(const short8*)(Vs + (size_t)(kk * 4 + jo) * 512 + l * 8);
        oacc[jo] = __builtin_amdgcn_mfma_f32_16x16x32_bf16(pa, bv, oacc[jo], 0, 0, 0);
      }
      __builtin_amdgcn_s_setprio(0);
    }
    const int q0 = t * 16;
#pragma unroll
    for (int jo = 0; jo < 4; ++jo) {
      const int kc = h * 2 + (jo >> 1);
      const int lgp = (jo & 1) * 2 + (lr >> 3);
      const int e = lr & 7;
#pragma unroll
      for (int v = 0; v < 4; ++v) {
        int n = q0 + lg * 4 + v;
        if (n < 197) {
          int m = b * 197 + n;
          Apk[((size_t)(kc * 788 + (m >> 4)) * 64 + (m & 15) + 16 * lgp) * 8 + e] = f2bf(oacc[jo][v]);
        }
      }
    }
  }
}

extern "C" void kernel_launch(void* const* d_in, const int* in_sizes, int n_in,
                              void* d_out, int out_size, void* d_ws, size_t ws_size,
                              hipStream_t stream) {
  const float* x      = (const float*)d_in[0];
  const float* qkv_w  = (const float*)d_in[1];
  const float* qkv_b  = (const float*)d_in[2];
  const float* qkv_la = (const float*)d_in[3];
  const float* qkv_lb = (const float*)d_in[4];
  const float* out_w  = (const float*)d_in[5];
  const float* out_b  = (const float*)d_in[6];
  const float* out_la = (const float*)d_in[7];
  const float* out_lb = (const float*)d_in[8];
  float* out = (float*)d_out;

  char* p = (char*)d_ws;
  auto carve = [&](size_t bytes) {
    char* r = p;
    p += (bytes + 255) & ~(size_t)255;
    return r;
  };
  unsigned short* Apk  = (unsigned short*)carve((size_t)788 * 24 * 512 * 2 + 32768);
  unsigned short* Wqpk = (unsigned short*)carve((size_t)144 * 24 * 512 * 2);
  unsigned short* Wopk = (unsigned short*)carve((size_t)48 * 24 * 512 * 2);
  unsigned short* Qpk  = (unsigned short*)carve((size_t)768 * 14336 * 2);
  unsigned short* Kpk  = (unsigned short*)carve((size_t)768 * 14336 * 2);
  unsigned short* Vtpk = (unsigned short*)carve((size_t)768 * 14336 * 2);

  // prep: 4728 (x-pack) + 864 (qkv_w fold) + 288 (out_w fold) + 192 (V pads)
  k_prep4<<<6072, 256, 0, stream>>>(x, qkv_w, out_w, qkv_la, qkv_lb, out_la, out_lb,
                                    Apk, Wqpk, Wopk, Vtpk);
  // qkv: 50 mg x 36 nt; 8-slot LDS, half-window refill, 4 blocks/CU
  k_gp7<0, 36, 144><<<50 * 36, 256, 0, stream>>>(Apk, Wqpk, qkv_b, Qpk, Kpk, Vtpk, nullptr);
  // attention: block per (b,h), K+V staged, chunked P (72KB LDS -> 2 blocks/CU)
  k_attn_c<<<768, 512, 0, stream>>>(Qpk, Kpk, Vtpk, Apk);  // Apk now holds packed attn-out
  // out: 50 mg x 12 nt
  k_gp7<1, 12, 48><<<50 * 12, 256, 0, stream>>>(Apk, Wopk, out_b, nullptr, nullptr, nullptr, out);
}